// Round 1
// baseline (989.058 us; speedup 1.0000x reference)
//
#include <hip/hip_runtime.h>

#define NS 32768
#define NLEV 4
#define NF 512
#define HID 512
#define VQD 64
#define CBS 4096

typedef __attribute__((ext_vector_type(8))) short bf16x8;
typedef __attribute__((ext_vector_type(4))) float f32x4;

#define MFMA16(a, b, c) __builtin_amdgcn_mfma_f32_16x16x32_bf16(a, b, c, 0, 0, 0)

__device__ inline unsigned short f2bf(float f) {
    unsigned int u = __float_as_uint(f);
    unsigned int r = (u + 0x7FFFu + ((u >> 16) & 1u)) >> 16;
    return (unsigned short)r;
}
__device__ inline float bf2f(unsigned short s) {
    return __uint_as_float(((unsigned int)s) << 16);
}

// async global->LDS, 16B per lane; lds base must be wave-uniform
__device__ __forceinline__ void gl16(const void* g, void* l) {
    __builtin_amdgcn_global_load_lds(
        (const __attribute__((address_space(1))) unsigned int*)g,
        (__attribute__((address_space(3))) unsigned int*)l, 16, 0, 0);
}

// ---------------- prep kernels ----------------

__global__ void transpose_all(const float* __restrict__ ew1, const float* __restrict__ ew2,
                              const float* __restrict__ dw1, const float* __restrict__ dw2,
                              unsigned short* __restrict__ ew1t, unsigned short* __restrict__ ew2t,
                              unsigned short* __restrict__ dw1t, unsigned short* __restrict__ dw2t) {
    long i = (long)blockIdx.x * 256 + threadIdx.x;
    const long s1 = (long)NLEV * NF * HID;
    const long s2 = (long)NLEV * HID * VQD;
    const long s3 = (long)NLEV * VQD * HID;
    const long s4 = (long)NLEV * HID * NF;
    const float* src;
    unsigned short* dst;
    int R, C;
    if (i < s1) { src = ew1; dst = ew1t; R = NF; C = HID; }
    else if (i < s1 + s2) { i -= s1; src = ew2; dst = ew2t; R = HID; C = VQD; }
    else if (i < s1 + s2 + s3) { i -= s1 + s2; src = dw1; dst = dw1t; R = VQD; C = HID; }
    else if (i < s1 + s2 + s3 + s4) { i -= s1 + s2 + s3; src = dw2; dst = dw2t; R = HID; C = NF; }
    else return;
    int r = (int)(i % R);
    long t = i / R;
    int c = (int)(t % C);
    int b = (int)(t / C);
    dst[i] = f2bf(src[((long)b * R + r) * C + c]);
}

__global__ void cb_prep(const float* __restrict__ cb, unsigned short* __restrict__ cbb,
                        float* __restrict__ cbn) {
    int i = blockIdx.x * 256 + threadIdx.x;  // l*CBS + n
    if (i >= NLEV * CBS) return;
    const float* row = cb + (long)i * VQD;
    float s = 0.f;
    for (int k = 0; k < VQD; k++) {
        float v = row[k];
        s += v * v;
        cbb[(long)i * VQD + k] = f2bf(v);
    }
    cbn[i] = s;
}

// all levels: x[n][l][f] fp32 -> xb[l][n][f] bf16
__global__ void xconv(const float* __restrict__ x, unsigned short* __restrict__ xb) {
    long i = (long)blockIdx.x * 256 + threadIdx.x;  // one per 8 elements
    int l = (int)(i / ((long)NS * (NF / 8)));
    long rem = i % ((long)NS * (NF / 8));
    int n = (int)(rem >> 6);
    int f8 = ((int)rem & 63) * 8;
    const float* src = x + ((long)n * NLEV + l) * NF + f8;
    float4 f0 = *(const float4*)src;
    float4 f1 = *(const float4*)(src + 4);
    short t[8];
    t[0] = (short)f2bf(f0.x); t[1] = (short)f2bf(f0.y); t[2] = (short)f2bf(f0.z); t[3] = (short)f2bf(f0.w);
    t[4] = (short)f2bf(f1.x); t[5] = (short)f2bf(f1.y); t[6] = (short)f2bf(f1.z); t[7] = (short)f2bf(f1.w);
    *(int4*)(xb + ((long)l * NS + n) * NF + f8) = *(const int4*)t;
}

// ---------------- fused encoder: enc1 + enc2 + VQ argmin + commit ----------------
// block = 128 rows, 512 threads (8 waves). LDS: Hs = 16 k-slices of [128][32] bf16.
// P1: h = relu(xb @ w1 + b1). k-outer, all 4 col-panels accumulated in regs
//     (acc[4][4][2] = 128 VGPR), staging A->slice (s&1), B panel j -> slice 2+2j+(s&1),
//     2-deep pipeline (stage s+1 under mfma s). h written once into slices [4j+wn].
// P2: z = h @ w2 + b2, A read from Hs (no staging), B dbuf in Zst.
// P3: z -> slices 0,1 (bf16) + ||z||^2; P4: VQ argmin, codebook dbuf in slices 2,3.
__global__ __launch_bounds__(512) void enc_fused(
    const unsigned short* __restrict__ xb, const unsigned short* __restrict__ w1t,
    const float* __restrict__ b1, const unsigned short* __restrict__ w2t,
    const float* __restrict__ b2, const unsigned short* __restrict__ cbb,
    const float* __restrict__ cbn, int* __restrict__ idxo, float* __restrict__ accum) {
    __shared__ __align__(16) short Hs[16 * 4096];
    __shared__ __align__(16) short Zst[2 * 2048];
    __shared__ float znp[2][128];
    __shared__ float zn2[128];
    __shared__ float cred;

    const int lvl = blockIdx.y;
    const int m0 = blockIdx.x * 128;
    xb += (long)lvl * NS * NF;
    w1t += (long)lvl * HID * NF;
    b1 += (long)lvl * HID;
    w2t += (long)lvl * VQD * HID;
    b2 += (long)lvl * VQD;
    cbb += (long)lvl * CBS * VQD;
    cbn += (long)lvl * CBS;
    idxo += (long)lvl * NS;

    const int tid = threadIdx.x;
    const int wave = tid >> 6, lane = tid & 63, quad = lane >> 4, lr = lane & 15;
    const int wm = wave >> 2, wn = wave & 3;  // rows 2x64, cols 4x32 (panels) / 4x16 (z)
    const int lrow = lane >> 2;
    const int lcol = (lane & 3) * 8;

    if (tid == 0) cred = 0.f;

    // ---------- P1 ----------
    f32x4 acc[4][4][2];
#pragma unroll
    for (int j = 0; j < 4; j++)
#pragma unroll
        for (int mt = 0; mt < 4; mt++) {
            acc[j][mt][0] = (f32x4){0.f, 0.f, 0.f, 0.f};
            acc[j][mt][1] = (f32x4){0.f, 0.f, 0.f, 0.f};
        }

    const unsigned short* ga = xb + (long)(m0 + wave * 16 + lrow) * NF + lcol;
    auto stage1 = [&](int s) {
        const int pi = s & 1;
        gl16(ga + s * 32, &Hs[pi * 4096 + wave * 16 * 32]);
#pragma unroll
        for (int j = 0; j < 4; j++)
            gl16(w1t + (long)(j * 128 + wave * 16 + lrow) * NF + s * 32 + lcol,
                 &Hs[(2 + 2 * j + pi) * 4096 + wave * 16 * 32]);
    };
    stage1(0);
#pragma unroll 2
    for (int s = 0; s < 16; s++) {
        __syncthreads();
        if (s < 15) stage1(s + 1);
        const int pi = s & 1;
        bf16x8 af[4];
#pragma unroll
        for (int mt = 0; mt < 4; mt++)
            af[mt] = *(const bf16x8*)&Hs[pi * 4096 + (wm * 64 + mt * 16 + lr) * 32 + quad * 8];
#pragma unroll
        for (int j = 0; j < 4; j++) {
            bf16x8 bf0 = *(const bf16x8*)&Hs[(2 + 2 * j + pi) * 4096 + (wn * 32 + lr) * 32 + quad * 8];
            bf16x8 bf1 = *(const bf16x8*)&Hs[(2 + 2 * j + pi) * 4096 + (wn * 32 + 16 + lr) * 32 + quad * 8];
#pragma unroll
            for (int mt = 0; mt < 4; mt++) {
                acc[j][mt][0] = MFMA16(af[mt], bf0, acc[j][mt][0]);
                acc[j][mt][1] = MFMA16(af[mt], bf1, acc[j][mt][1]);
            }
        }
    }
    __syncthreads();  // all LDS reads done before h overwrites the slices
#pragma unroll
    for (int j = 0; j < 4; j++) {
        float bv0 = b1[j * 128 + wn * 32 + lr];
        float bv1 = b1[j * 128 + wn * 32 + 16 + lr];
        short* hs = &Hs[(4 * j + wn) * 4096];
#pragma unroll
        for (int mt = 0; mt < 4; mt++)
#pragma unroll
            for (int r = 0; r < 4; r++) {
                int row = wm * 64 + mt * 16 + quad * 4 + r;
                float v0 = acc[j][mt][0][r] + bv0; v0 = v0 > 0.f ? v0 : 0.f;
                float v1 = acc[j][mt][1][r] + bv1; v1 = v1 > 0.f ? v1 : 0.f;
                hs[row * 32 + lr] = (short)f2bf(v0);
                hs[row * 32 + 16 + lr] = (short)f2bf(v1);
            }
    }

    // ---------- P2: z = h @ w2 + b2 ----------
    f32x4 az[4];
#pragma unroll
    for (int mt = 0; mt < 4; mt++) az[mt] = (f32x4){0.f, 0.f, 0.f, 0.f};
    auto stageZ = [&](int s) {
        if (wave < 4)
            gl16(w2t + (long)(wave * 16 + lrow) * HID + s * 32 + lcol,
                 &Zst[(s & 1) * 2048 + wave * 16 * 32]);
    };
    stageZ(0);
#pragma unroll 2
    for (int s = 0; s < 16; s++) {
        __syncthreads();  // first iter also orders the h-writes
        if (s < 15) stageZ(s + 1);
        bf16x8 bz = *(const bf16x8*)&Zst[(s & 1) * 2048 + (wn * 16 + lr) * 32 + quad * 8];
#pragma unroll
        for (int mt = 0; mt < 4; mt++) {
            bf16x8 af = *(const bf16x8*)&Hs[s * 4096 + (wm * 64 + mt * 16 + lr) * 32 + quad * 8];
            az[mt] = MFMA16(af, bz, az[mt]);
        }
    }
    __syncthreads();
    {  // z (bf16) into slices 0,1 in VQ A-panel layout
        float bz0 = b2[wn * 16 + lr];
        const int col = wn * 16 + lr;
        short* zs = &Hs[(col >> 5) * 4096];
        const int c32 = col & 31;
#pragma unroll
        for (int mt = 0; mt < 4; mt++)
#pragma unroll
            for (int r = 0; r < 4; r++) {
                int row = wm * 64 + mt * 16 + quad * 4 + r;
                zs[row * 32 + c32] = (short)f2bf(az[mt][r] + bz0);
            }
    }
    __syncthreads();

    // ---------- P3/P4: VQ argmin (codebook dbuf in slices 2,3) ----------
    auto stageC = [&](int t) {
        gl16(cbb + (long)(t * 64 + wn * 16 + lrow) * VQD + wm * 32 + lcol,
             &Hs[(2 + (t & 1)) * 4096 + wm * 2048 + wn * 512]);
    };
    stageC(0);
    if (tid < 256) {
        int row = tid >> 1, p = tid & 1;
        const short* zr = &Hs[p * 4096 + row * 32];
        float s2 = 0.f;
#pragma unroll
        for (int j2 = 0; j2 < 32; j2++) {
            float f = bf2f((unsigned short)zr[j2]);
            s2 += f * f;
        }
        znp[p][row] = s2;
    }
    bf16x8 a0 = *(const bf16x8*)&Hs[(wave * 16 + lr) * 32 + quad * 8];
    bf16x8 a1 = *(const bf16x8*)&Hs[4096 + (wave * 16 + lr) * 32 + quad * 8];
    __syncthreads();  // znp visible; stageC(0) drained
    if (tid < 128) zn2[tid] = znp[0][tid] + znp[1][tid];

    float minv[4] = {1e30f, 1e30f, 1e30f, 1e30f};
    int mini[4] = {0, 0, 0, 0};
#pragma unroll 2
    for (int t = 0; t < CBS / 64; t++) {
        if (t) __syncthreads();
        if (t < CBS / 64 - 1) stageC(t + 1);
        const short* Cb = &Hs[(2 + (t & 1)) * 4096];
#pragma unroll
        for (int nt = 0; nt < 4; nt++) {
            bf16x8 c0 = *(const bf16x8*)&Cb[(nt * 16 + lr) * 32 + quad * 8];
            bf16x8 c1 = *(const bf16x8*)&Cb[2048 + (nt * 16 + lr) * 32 + quad * 8];
            f32x4 d4 = {0.f, 0.f, 0.f, 0.f};
            d4 = MFMA16(a0, c0, d4);
            d4 = MFMA16(a1, c1, d4);
            int n = t * 64 + nt * 16 + lr;
            float cn = cbn[n];
#pragma unroll
            for (int r = 0; r < 4; r++) {
                float d = fmaf(-2.f, d4[r], cn);
                if (d < minv[r]) { minv[r] = d; mini[r] = n; }
            }
        }
    }

    // ---------- P5: reduce, write idx, commit ----------
    float csum = 0.f;
#pragma unroll
    for (int r = 0; r < 4; r++) {
        float v = minv[r];
        int ix = mini[r];
#pragma unroll
        for (int off = 8; off; off >>= 1) {
            float ov = __shfl_xor(v, off, 64);
            int oi = __shfl_xor(ix, off, 64);
            if (ov < v || (ov == v && oi < ix)) { v = ov; ix = oi; }
        }
        if (lr == 0) {
            int row = wave * 16 + quad * 4 + r;
            idxo[m0 + row] = ix;
            csum += v + zn2[row];
        }
    }
    if (lvl == NLEV - 1) {
        if (lr == 0) atomicAdd(&cred, csum);
        __syncthreads();
        if (tid == 0) atomicAdd(accum + 1, cred);
    }
}

// ---------------- fused decoder: dec1 (gather) + dec2 + MSE ----------------
// P1: h2 = relu(cb[idx] @ w1 + b1) built panel-by-panel straight into the LDS
//     A-slices (staging uses the panel's own region before it holds h2).
// P2: MSE GEMM: A from Hs (no staging), B (dw2t, L2-resident) dbuf in Bst.
__global__ __launch_bounds__(512) void dec_fused(
    const unsigned short* __restrict__ cbb, const int* __restrict__ idx,
    const unsigned short* __restrict__ w1t, const float* __restrict__ b1,
    const unsigned short* __restrict__ w2t, const float* __restrict__ b2,
    const unsigned short* __restrict__ xref, float* __restrict__ accum) {
    __shared__ __align__(16) short Hs[16 * 4096];
    __shared__ __align__(16) short Bst[2 * 4096];
    __shared__ float red[8];

    const int lvl = blockIdx.y;
    const int m0 = blockIdx.x * 128;
    cbb += (long)lvl * CBS * VQD;
    idx += (long)lvl * NS;
    w1t += (long)lvl * HID * VQD;
    b1 += (long)lvl * HID;
    w2t += (long)lvl * NF * HID;
    b2 += (long)lvl * NF;
    xref += (long)lvl * NS * NF;

    const int tid = threadIdx.x;
    const int wave = tid >> 6, lane = tid & 63, quad = lane >> 4, lr = lane & 15;
    const int wm = wave >> 2, wn = wave & 3;
    const int lrow = lane >> 2;
    const int lcol = (lane & 3) * 8;

    const long idxv = idx[m0 + wave * 16 + lrow];

    // ---------- P1 ----------
    auto stageD = [&](int j) {
#pragma unroll
        for (int p = 0; p < 2; p++) {
            gl16(cbb + idxv * VQD + p * 32 + lcol, &Hs[(4 * j + p) * 4096 + wave * 16 * 32]);
            gl16(w1t + (long)(j * 128 + wave * 16 + lrow) * VQD + p * 32 + lcol,
                 &Hs[(4 * j + 2 + p) * 4096 + wave * 16 * 32]);
        }
    };
    stageD(0);
#pragma unroll
    for (int j = 0; j < 4; j++) {
        f32x4 acc[4][2];
#pragma unroll
        for (int mt = 0; mt < 4; mt++) {
            acc[mt][0] = (f32x4){0.f, 0.f, 0.f, 0.f};
            acc[mt][1] = (f32x4){0.f, 0.f, 0.f, 0.f};
        }
        __syncthreads();
        if (j < 3) stageD(j + 1);
#pragma unroll
        for (int p = 0; p < 2; p++) {
            bf16x8 bf0 = *(const bf16x8*)&Hs[(4 * j + 2 + p) * 4096 + (wn * 32 + lr) * 32 + quad * 8];
            bf16x8 bf1 = *(const bf16x8*)&Hs[(4 * j + 2 + p) * 4096 + (wn * 32 + 16 + lr) * 32 + quad * 8];
#pragma unroll
            for (int mt = 0; mt < 4; mt++) {
                bf16x8 af = *(const bf16x8*)&Hs[(4 * j + p) * 4096 + (wm * 64 + mt * 16 + lr) * 32 + quad * 8];
                acc[mt][0] = MFMA16(af, bf0, acc[mt][0]);
                acc[mt][1] = MFMA16(af, bf1, acc[mt][1]);
            }
        }
        __syncthreads();
        float bv0 = b1[j * 128 + wn * 32 + lr];
        float bv1 = b1[j * 128 + wn * 32 + 16 + lr];
        short* hs = &Hs[(4 * j + wn) * 4096];
#pragma unroll
        for (int mt = 0; mt < 4; mt++)
#pragma unroll
            for (int r = 0; r < 4; r++) {
                int row = wm * 64 + mt * 16 + quad * 4 + r;
                float v0 = acc[mt][0][r] + bv0; v0 = v0 > 0.f ? v0 : 0.f;
                float v1 = acc[mt][1][r] + bv1; v1 = v1 > 0.f ? v1 : 0.f;
                hs[row * 32 + lr] = (short)f2bf(v0);
                hs[row * 32 + 16 + lr] = (short)f2bf(v1);
            }
    }

    // ---------- P2: fused MSE GEMM ----------
    auto stageB = [&](int g) {
        gl16(w2t + (long)((g >> 4) * 128 + wave * 16 + lrow) * HID + (g & 15) * 32 + lcol,
             &Bst[(g & 1) * 4096 + wave * 16 * 32]);
    };
    stageB(0);
    float lsum = 0.f;
    f32x4 acc2[4][2];
#pragma unroll
    for (int mt = 0; mt < 4; mt++) {
        acc2[mt][0] = (f32x4){0.f, 0.f, 0.f, 0.f};
        acc2[mt][1] = (f32x4){0.f, 0.f, 0.f, 0.f};
    }
#pragma unroll 2
    for (int g = 0; g < 64; g++) {
        __syncthreads();
        if (g < 63) stageB(g + 1);
        const int s = g & 15;
        bf16x8 bf0 = *(const bf16x8*)&Bst[(g & 1) * 4096 + (wn * 32 + lr) * 32 + quad * 8];
        bf16x8 bf1 = *(const bf16x8*)&Bst[(g & 1) * 4096 + (wn * 32 + 16 + lr) * 32 + quad * 8];
#pragma unroll
        for (int mt = 0; mt < 4; mt++) {
            bf16x8 af = *(const bf16x8*)&Hs[s * 4096 + (wm * 64 + mt * 16 + lr) * 32 + quad * 8];
            acc2[mt][0] = MFMA16(af, bf0, acc2[mt][0]);
            acc2[mt][1] = MFMA16(af, bf1, acc2[mt][1]);
        }
        if (s == 15) {
            const int jj = g >> 4;
            float bv0 = b2[jj * 128 + wn * 32 + lr];
            float bv1 = b2[jj * 128 + wn * 32 + 16 + lr];
#pragma unroll
            for (int mt = 0; mt < 4; mt++)
#pragma unroll
                for (int r = 0; r < 4; r++) {
                    long row = m0 + wm * 64 + mt * 16 + quad * 4 + r;
                    int c0 = jj * 128 + wn * 32 + lr;
                    float v0 = acc2[mt][0][r] + bv0 - bf2f(xref[row * NF + c0]);
                    float v1 = acc2[mt][1][r] + bv1 - bf2f(xref[row * NF + c0 + 16]);
                    lsum += v0 * v0 + v1 * v1;
                    acc2[mt][0][r] = 0.f;
                    acc2[mt][1][r] = 0.f;
                }
        }
    }
#pragma unroll
    for (int off = 32; off; off >>= 1) lsum += __shfl_down(lsum, off, 64);
    if (lane == 0) red[wave] = lsum;
    __syncthreads();
    if (tid == 0) {
        float s2 = 0.f;
#pragma unroll
        for (int w = 0; w < 8; w++) s2 += red[w];
        atomicAdd(accum, s2);
    }
}

__global__ void finalize_k(const float* __restrict__ accum, float* __restrict__ out) {
    out[0] = accum[0] / ((float)NS * NF * NLEV);
    out[1] = 0.25f * accum[1] / ((float)NS * VQD * NLEV);
}

// ---------------- launch ----------------
extern "C" void kernel_launch(void* const* d_in, const int* in_sizes, int n_in, void* d_out,
                              int out_size, void* d_ws, size_t ws_size, hipStream_t stream) {
    const float* x = (const float*)d_in[0];
    const float* enc_w1 = (const float*)d_in[1];
    const float* enc_b1 = (const float*)d_in[2];
    const float* enc_w2 = (const float*)d_in[3];
    const float* enc_b2 = (const float*)d_in[4];
    const float* dec_w1 = (const float*)d_in[5];
    const float* dec_b1 = (const float*)d_in[6];
    const float* dec_w2 = (const float*)d_in[7];
    const float* dec_b2 = (const float*)d_in[8];
    const float* cb = (const float*)d_in[9];

    char* ws = (char*)d_ws;
    size_t o = 0;
    float* accum = (float*)(ws + o); o += 256;
    unsigned short* enc_w1t = (unsigned short*)(ws + o); o += (size_t)NLEV * HID * NF * 2;
    unsigned short* enc_w2t = (unsigned short*)(ws + o); o += (size_t)NLEV * VQD * HID * 2;
    unsigned short* dec_w1t = (unsigned short*)(ws + o); o += (size_t)NLEV * HID * VQD * 2;
    unsigned short* dec_w2t = (unsigned short*)(ws + o); o += (size_t)NLEV * NF * HID * 2;
    unsigned short* cbb = (unsigned short*)(ws + o); o += (size_t)NLEV * CBS * VQD * 2;
    float* cbn = (float*)(ws + o); o += (size_t)NLEV * CBS * 4;
    unsigned short* xb = (unsigned short*)(ws + o); o += (size_t)NLEV * NS * NF * 2;  // 134 MB
    int* idxp = (int*)(ws + o); o += (size_t)NLEV * NS * 4;

    hipMemsetAsync(accum, 0, 8, stream);

    transpose_all<<<(2 * NLEV * NF * HID + 2 * NLEV * HID * VQD + 255) / 256, 256, 0, stream>>>(
        enc_w1, enc_w2, dec_w1, dec_w2, enc_w1t, enc_w2t, dec_w1t, dec_w2t);
    cb_prep<<<(NLEV * CBS + 255) / 256, 256, 0, stream>>>(cb, cbb, cbn);
    xconv<<<(int)(((long)NLEV * NS * (NF / 8) + 255) / 256), 256, 0, stream>>>(x, xb);

    enc_fused<<<dim3(NS / 128, NLEV), 512, 0, stream>>>(
        xb, enc_w1t, enc_b1, enc_w2t, enc_b2, cbb, cbn, idxp, accum);
    dec_fused<<<dim3(NS / 128, NLEV), 512, 0, stream>>>(
        cbb, idxp, dec_w1t, dec_b1, dec_w2t, dec_b2, xb, accum);

    finalize_k<<<1, 1, 0, stream>>>(accum, (float*)d_out);
}